// Round 2
// 1110.661 us; speedup vs baseline: 1.0303x; 1.0303x over previous
//
#include <hip/hip_runtime.h>
#include <stdint.h>

#define H 1024
#define T 4096
#define NV 32000
#define EPSF 1.1920928955078125e-07f

typedef __attribute__((ext_vector_type(8))) short short8;
typedef __attribute__((ext_vector_type(4))) float f32x4;

struct __align__(8) US4 { unsigned short x, y, z, w; };

__device__ __forceinline__ unsigned short f2bf(float f) {
    union { float f; unsigned int u; } v; v.f = f;
    unsigned int u = v.u;
    unsigned int r = (u + 0x7FFFu + ((u >> 16) & 1u)) >> 16;  // RNE
    return (unsigned short)r;
}

__device__ __forceinline__ float wsum(float v) {
#pragma unroll
    for (int o = 32; o; o >>= 1) v += __shfl_down(v, o, 64);
    return v;
}

// ---------------- conversion kernels ----------------
__global__ __launch_bounds__(256) void convf2b(const float* __restrict__ in,
                                               unsigned short* __restrict__ out,
                                               long long n) {
    long long i = ((long long)blockIdx.x * 256 + threadIdx.x) * 4;
    long long stride = (long long)gridDim.x * 1024;
    for (; i < n; i += stride) {
        float4 v = *(const float4*)&in[i];
        US4 o;
        o.x = f2bf(v.x); o.y = f2bf(v.y); o.z = f2bf(v.z); o.w = f2bf(v.w);
        *(US4*)&out[i] = o;
    }
}

// eu_w [8,1024,128] -> W2 [h][n*128+i] bf16
__global__ __launch_bounds__(256) void trans_euw(const float* __restrict__ euw,
                                                 unsigned short* __restrict__ out) {
    int h = blockIdx.x, tid = threadIdx.x;
#pragma unroll
    for (int j = 0; j < 4; j++) {
        int ni = tid + j * 256;
        int n = ni >> 7, i = ni & 127;
        out[(size_t)h * 1024 + ni] = f2bf(euw[(size_t)n * 131072 + (size_t)h * 128 + i]);
    }
}

// ---------------- LoRA stage 1: tqkv[t][0..23] = x[t] . {qA,kA,vA} rows ----------------
__global__ __launch_bounds__(256) void lora_a(const float* __restrict__ x,
                                              const float* __restrict__ qA,
                                              const float* __restrict__ kA,
                                              const float* __restrict__ vA,
                                              float* __restrict__ tqkv) {
    int t = blockIdx.x, tid = threadIdx.x;
    int wave = tid >> 6, lane = tid & 63;
    const float* xr = x + (size_t)t * H;
    float s[24];
#pragma unroll
    for (int r = 0; r < 24; r++) s[r] = 0.f;
#pragma unroll
    for (int j = 0; j < 4; j++) {
        int h = tid + j * 256;
        float xv = xr[h];
#pragma unroll
        for (int r = 0; r < 8; r++) {
            s[r]      += xv * qA[r * H + h];
            s[8 + r]  += xv * kA[r * H + h];
            s[16 + r] += xv * vA[r * H + h];
        }
    }
#pragma unroll
    for (int r = 0; r < 24; r++) s[r] = wsum(s[r]);
    __shared__ float red[4][24];
    if (lane == 0) {
#pragma unroll
        for (int r = 0; r < 24; r++) red[wave][r] = s[r];
    }
    __syncthreads();
    if (tid < 24)
        tqkv[(size_t)t * 24 + tid] = red[0][tid] + red[1][tid] + red[2][tid] + red[3][tid];
}

// ---------------- fused: qkv-LoRA-B, o-LoRA, residual, RMSNorm1, router, top-2 ----------------
__global__ __launch_bounds__(256) void fused1(
    const float* __restrict__ x, const float* __restrict__ tqkv,
    const float* __restrict__ qB, const float* __restrict__ kB, const float* __restrict__ vB,
    const float* __restrict__ oA, const float* __restrict__ oB,
    const float* __restrict__ n1w, const float* __restrict__ rw,
    float* __restrict__ x1, unsigned short* __restrict__ x1b,
    int* __restrict__ topi, float* __restrict__ topw) {
    const int t = blockIdx.x, tid = threadIdx.x;
    const int wave = tid >> 6, lane = tid & 63;
    __shared__ float tq[24];
    __shared__ float red[4][8];
    __shared__ float t2s[8];
    if (tid < 24) tq[tid] = tqkv[(size_t)t * 24 + tid];
    __syncthreads();
    const float* xr = x + (size_t)t * H;
    float p2[8] = {0, 0, 0, 0, 0, 0, 0, 0};
#pragma unroll
    for (int j = 0; j < 4; j++) {
        int h = tid + j * 256;
        float s = 0.f;
#pragma unroll
        for (int r = 0; r < 8; r++) {
            s += tq[r] * qB[h * 8 + r];
            s += tq[8 + r] * kB[h * 8 + r];
            s += tq[16 + r] * vB[h * 8 + r];
        }
        s *= 2.0f;  // SCALE on inner LoRAs
#pragma unroll
        for (int r = 0; r < 8; r++) p2[r] += s * oA[r * H + h];
    }
#pragma unroll
    for (int r = 0; r < 8; r++) p2[r] = wsum(p2[r]);
    if (lane == 0) {
#pragma unroll
        for (int r = 0; r < 8; r++) red[wave][r] = p2[r];
    }
    __syncthreads();
    if (tid < 8) t2s[tid] = red[0][tid] + red[1][tid] + red[2][tid] + red[3][tid];
    __syncthreads();
    float t2l[8];
#pragma unroll
    for (int r = 0; r < 8; r++) t2l[r] = t2s[r];

    float z[4]; float ss = 0.f;
#pragma unroll
    for (int j = 0; j < 4; j++) {
        int h = tid + j * 256;
        float a = 0.f;
#pragma unroll
        for (int r = 0; r < 8; r++) a += t2l[r] * oB[h * 8 + r];
        float zz = xr[h] + 2.0f * a;  // SCALE on outer LoRA
        z[j] = zz; ss += zz * zz;
    }
    ss = wsum(ss);
    __syncthreads();  // red reuse
    if (lane == 0) red[wave][0] = ss;
    __syncthreads();
    float rstd = rsqrtf((red[0][0] + red[1][0] + red[2][0] + red[3][0]) * (1.0f / H) + EPSF);

    float pr[8] = {0, 0, 0, 0, 0, 0, 0, 0};
#pragma unroll
    for (int j = 0; j < 4; j++) {
        int h = tid + j * 256;
        float xv = z[j] * rstd * n1w[h];
        x1[(size_t)t * H + h] = xv;
        x1b[(size_t)t * H + h] = f2bf(xv);
#pragma unroll
        for (int n = 0; n < 8; n++) pr[n] += xv * rw[n * H + h];
    }
#pragma unroll
    for (int n = 0; n < 8; n++) pr[n] = wsum(pr[n]);
    __syncthreads();  // red reuse
    if (lane == 0) {
#pragma unroll
        for (int n = 0; n < 8; n++) red[wave][n] = pr[n];
    }
    __syncthreads();
    if (tid == 0) {
        float l[8];
#pragma unroll
        for (int n = 0; n < 8; n++) l[n] = red[0][n] + red[1][n] + red[2][n] + red[3][n];
        int i0 = 0;
        for (int n = 1; n < 8; n++) if (l[n] > l[i0]) i0 = n;
        int i1 = (i0 == 0) ? 1 : 0;
        for (int n = 0; n < 8; n++) if (n != i0 && l[n] > l[i1]) i1 = n;
        float w0 = 1.f / (1.f + expf(l[i1] - l[i0]));  // softmax of top-2, l[i0] >= l[i1]
        topi[2 * t] = i0; topi[2 * t + 1] = i1;
        topw[2 * t] = w0; topw[2 * t + 1] = 1.f - w0;
    }
}

// ---------------- MoE activation: silu + top2 mask/weight -> bf16 ----------------
__global__ __launch_bounds__(256) void moe_act(const float* __restrict__ Gall,
                                               const float* __restrict__ egb,
                                               const int* __restrict__ topi,
                                               const float* __restrict__ topw,
                                               unsigned short* __restrict__ GWb) {
    int t = blockIdx.x, tid = threadIdx.x;
    int i0 = topi[2 * t], i1 = topi[2 * t + 1];
    float w0 = topw[2 * t], w1 = topw[2 * t + 1];
#pragma unroll
    for (int j = 0; j < 4; j++) {
        int ni = tid + j * 256;
        int n = ni >> 7;
        float w = (n == i0) ? w0 : ((n == i1) ? w1 : 0.f);
        float g = Gall[(size_t)t * 1024 + ni] + egb[ni];
        float sv = g / (1.f + expf(-g));  // silu
        GWb[(size_t)t * 1024 + ni] = f2bf(sv * w);
    }
}

// ---------------- residual + expert-bias + RMSNorm2 -> x2 bf16 ----------------
__global__ __launch_bounds__(256) void rms2(const float* __restrict__ x1,
                                            const float* __restrict__ Y,
                                            const float* __restrict__ eub,
                                            const int* __restrict__ topi,
                                            const float* __restrict__ topw,
                                            const float* __restrict__ n2w,
                                            unsigned short* __restrict__ x2b) {
    int t = blockIdx.x, tid = threadIdx.x, wave = tid >> 6, lane = tid & 63;
    __shared__ float red[4];
    int i0 = topi[2 * t], i1 = topi[2 * t + 1];
    float w0 = topw[2 * t], w1 = topw[2 * t + 1];
    float z[4]; float ss = 0.f;
#pragma unroll
    for (int j = 0; j < 4; j++) {
        int h = tid + j * 256;
        float zz = x1[(size_t)t * H + h] + Y[(size_t)t * H + h]
                 + w0 * eub[(size_t)i0 * H + h] + w1 * eub[(size_t)i1 * H + h];
        z[j] = zz; ss += zz * zz;
    }
    ss = wsum(ss);
    if (lane == 0) red[wave] = ss;
    __syncthreads();
    float rstd = rsqrtf((red[0] + red[1] + red[2] + red[3]) * (1.0f / H) + EPSF);
#pragma unroll
    for (int j = 0; j < 4; j++) {
        int h = tid + j * 256;
        x2b[(size_t)t * H + h] = f2bf(z[j] * rstd * n2w[h]);
    }
}

// ---------------- bf16 GEMM  C[M,N] = A[M,K] * B[N,K]^T  (m97 structure) ----------------
// NT: non-temporal C stores (C never re-read; keeps B resident in L2/L3).
// All launches have nwg % 8 == 0, so the simple XCD-chunked swizzle is bijective.
__device__ __forceinline__ void gload16(void* lds, const void* g) {
    __builtin_amdgcn_global_load_lds(
        (const __attribute__((address_space(1))) unsigned int*)g,
        (__attribute__((address_space(3))) unsigned int*)lds, 16, 0, 0);
}

template <bool NT>
__global__ __launch_bounds__(256) void gemm_bt(const unsigned short* __restrict__ A,
                                               const unsigned short* __restrict__ B,
                                               float* __restrict__ C,
                                               int M, int N, int K) {
    __shared__ __align__(16) unsigned short As[128 * 32];
    __shared__ __align__(16) unsigned short Bs[128 * 32];
    const int tid = threadIdx.x;
    const int wave = tid >> 6, lane = tid & 63;
    const int quad = lane >> 4, l16 = lane & 15;

    // XCD-aware chunked swizzle (T1, bijective since nwg % 8 == 0):
    // XCD k owns nwg/8 consecutive tiles in row-major tile order -> its A-tiles
    // stay L2-resident and B-tile reuse is temporally clustered.
    const int nwg = gridDim.x * gridDim.y;
    const int lid = blockIdx.y * gridDim.x + blockIdx.x;
    const int swz = (lid & 7) * (nwg >> 3) + (lid >> 3);
    const int bx = swz % gridDim.x, by = swz / gridDim.x;

    const int row0 = by * 128, col0 = bx * 128;
    const int wr = (wave >> 1) * 64, wc = (wave & 1) * 64;

    f32x4 acc[4][4];
#pragma unroll
    for (int i = 0; i < 4; i++)
#pragma unroll
        for (int j = 0; j < 4; j++) acc[i][j] = (f32x4){0.f, 0.f, 0.f, 0.f};

    for (int k0 = 0; k0 < K; k0 += 32) {
#pragma unroll
        for (int p = 0; p < 2; p++) {
            int L = p * 256 + tid;        // 0..511, 16B each
            int r = L >> 2, kk = (L & 3) * 8;
            gload16((char*)As + (size_t)(p * 256 + wave * 64) * 16,
                    &A[(size_t)(row0 + r) * K + k0 + kk]);
            gload16((char*)Bs + (size_t)(p * 256 + wave * 64) * 16,
                    &B[(size_t)(col0 + r) * K + k0 + kk]);
        }
        __syncthreads();  // drains vmcnt before barrier
        short8 af[4], bfrag[4];
#pragma unroll
        for (int i = 0; i < 4; i++)
            af[i] = *(const short8*)&As[(wr + i * 16 + l16) * 32 + quad * 8];
#pragma unroll
        for (int j = 0; j < 4; j++)
            bfrag[j] = *(const short8*)&Bs[(wc + j * 16 + l16) * 32 + quad * 8];
#pragma unroll
        for (int i = 0; i < 4; i++)
#pragma unroll
            for (int j = 0; j < 4; j++)
                acc[i][j] = __builtin_amdgcn_mfma_f32_16x16x32_bf16(af[i], bfrag[j], acc[i][j], 0, 0, 0);
        __syncthreads();
    }
    // C/D layout: col = lane&15, row = quad*4 + reg   [m89-verified]
#pragma unroll
    for (int i = 0; i < 4; i++) {
        int r0 = row0 + wr + i * 16 + quad * 4;
#pragma unroll
        for (int j = 0; j < 4; j++) {
            int c = col0 + wc + j * 16 + l16;
#pragma unroll
            for (int g = 0; g < 4; g++) {
                if (NT)
                    __builtin_nontemporal_store(acc[i][j][g], &C[(size_t)(r0 + g) * N + c]);
                else
                    C[(size_t)(r0 + g) * N + c] = acc[i][j][g];
            }
        }
    }
}

extern "C" void kernel_launch(void* const* d_in, const int* in_sizes, int n_in,
                              void* d_out, int out_size, void* d_ws, size_t ws_size,
                              hipStream_t stream) {
    const float* x   = (const float*)d_in[0];
    const float* qA  = (const float*)d_in[1];
    const float* qB  = (const float*)d_in[2];
    const float* kA  = (const float*)d_in[3];
    const float* kB  = (const float*)d_in[4];
    const float* vA  = (const float*)d_in[5];
    const float* vB  = (const float*)d_in[6];
    const float* oA  = (const float*)d_in[7];
    const float* oB  = (const float*)d_in[8];
    const float* n1w = (const float*)d_in[9];
    const float* n2w = (const float*)d_in[10];
    const float* rw  = (const float*)d_in[11];
    const float* egw = (const float*)d_in[12];
    const float* egb = (const float*)d_in[13];
    const float* euw = (const float*)d_in[14];
    const float* eub = (const float*)d_in[15];
    const float* hw  = (const float*)d_in[16];
    float* out = (float*)d_out;

    char* p = (char*)d_ws;
    auto alloc = [&](size_t bytes) {
        void* r = (void*)p;
        p += (bytes + 255) & ~(size_t)255;
        return r;
    };
    float* tqkv          = (float*)alloc((size_t)T * 24 * 4);
    float* x1            = (float*)alloc((size_t)T * H * 4);
    unsigned short* x1b  = (unsigned short*)alloc((size_t)T * H * 2);
    int* topi            = (int*)alloc((size_t)T * 2 * 4);
    float* topw          = (float*)alloc((size_t)T * 2 * 4);
    float* Gall          = (float*)alloc((size_t)T * 1024 * 4);
    unsigned short* GWb  = (unsigned short*)alloc((size_t)T * 1024 * 2);
    float* Y             = (float*)alloc((size_t)T * H * 4);
    unsigned short* x2b  = (unsigned short*)alloc((size_t)T * H * 2);
    unsigned short* egwb = (unsigned short*)alloc((size_t)1024 * 1024 * 2);
    unsigned short* euwT = (unsigned short*)alloc((size_t)1024 * 1024 * 2);
    unsigned short* hwb  = (unsigned short*)alloc((size_t)NV * H * 2);

    // weight conversions (independent)
    convf2b<<<1024, 256, 0, stream>>>(egw, egwb, (long long)1024 * 1024);
    trans_euw<<<1024, 256, 0, stream>>>(euw, euwT);
    convf2b<<<4096, 256, 0, stream>>>(hw, hwb, (long long)NV * H);

    // token pipeline
    lora_a<<<T, 256, 0, stream>>>(x, qA, kA, vA, tqkv);
    fused1<<<T, 256, 0, stream>>>(x, tqkv, qB, kB, vB, oA, oB, n1w, rw, x1, x1b, topi, topw);
    gemm_bt<false><<<dim3(1024 / 128, T / 128), 256, 0, stream>>>(x1b, egwb, Gall, T, 1024, 1024);
    moe_act<<<T, 256, 0, stream>>>(Gall, egb, topi, topw, GWb);
    gemm_bt<false><<<dim3(1024 / 128, T / 128), 256, 0, stream>>>(GWb, euwT, Y, T, 1024, 1024);
    rms2<<<T, 256, 0, stream>>>(x1, Y, eub, topi, topw, n2w, x2b);
    gemm_bt<true><<<dim3(NV / 128, T / 128), 256, 0, stream>>>(x2b, hwb, out, T, NV, 1024);
}